// Round 6
// baseline (459.070 us; speedup 1.0000x reference)
//
#include <hip/hip_runtime.h>
#include <hip/hip_fp16.h>

#define NN 100000
#define NE 3200000
#define FIN 300
#define HID 16
#define NC 10

#define NPB 64                  // nodes per bucket
#define NB 1563                 // ceil(NN / NPB)
#define NSEG 512                // edge segments
#define EPS (NE / NSEG)         // 6250 edges per segment
#define NCH 8                   // chunks for the seg-scan
#define SEGPC (NSEG / NCH)      // 64 segs per chunk
#define CAP 3072                // max bucket size (mean 2048, sd ~45; +22 sigma)
#define W1STRIDE 308            // 300 rounded to x4 with bank-skew (2-way only)

__device__ __forceinline__ float h2f_lo(int y) {
    __half_raw hr; hr.x = (unsigned short)(y & 0xFFFF);
    __half h; *(__half_raw*)&h = hr;
    return __half2float(h);
}
__device__ __forceinline__ int f2h_us(float f) {
    __half h = __float2half(f);
    return (int)(*(__half_raw*)&h).x;
}

// ---- phase 1: per-segment histogram over buckets ---------------------------

__global__ void k_hist(const int* __restrict__ col, int* __restrict__ hist) {
    __shared__ int bins[NB];
    int seg = blockIdx.x, tid = threadIdx.x;
    for (int i = tid; i < NB; i += 256) bins[i] = 0;
    __syncthreads();
    int base = seg * EPS;
    for (int k = tid; k < EPS; k += 256) atomicAdd(&bins[col[base + k] >> 6], 1);
    __syncthreads();
    for (int i = tid; i < NB; i += 256) hist[seg * NB + i] = bins[i];
}

// ---- phase 2: parallel scan of hist over segs ------------------------------

__global__ void k_psumA(const int* __restrict__ hist, int* __restrict__ psum) {
    int bin = blockIdx.x * 256 + threadIdx.x;
    int ch = blockIdx.y;
    if (bin >= NB) return;
    int s = 0;
    for (int seg = ch * SEGPC; seg < (ch + 1) * SEGPC; ++seg) s += hist[seg * NB + bin];
    psum[ch * NB + bin] = s;
}

__global__ void k_psumB(int* __restrict__ psum, int* __restrict__ bstart) {
    int bin = blockIdx.x * 256 + threadIdx.x;
    if (bin >= NB) return;
    int run = 0;
    #pragma unroll
    for (int ch = 0; ch < NCH; ++ch) {
        int v = psum[ch * NB + bin];
        psum[ch * NB + bin] = run;
        run += v;
    }
    bstart[bin] = run;
}

__global__ void k_scanBkt(int* __restrict__ bstart) {
    __shared__ int lsum[256];
    int t = threadIdx.x;
    const int M = (NB + 255) / 256;   // 7
    int base = t * M;
    int s = 0;
    for (int q = 0; q < M; ++q) { int i = base + q; if (i < NB) s += bstart[i]; }
    lsum[t] = s; __syncthreads();
    for (int off = 1; off < 256; off <<= 1) {
        int add = (t >= off) ? lsum[t - off] : 0;
        __syncthreads(); lsum[t] += add; __syncthreads();
    }
    int run = (t > 0) ? lsum[t - 1] : 0;
    for (int q = 0; q < M; ++q) {
        int i = base + q;
        if (i < NB) { int v = bstart[i]; bstart[i] = run; run += v; }
    }
    if (t == 255) bstart[NB] = run;   // = NE
}

__global__ void k_applyC(int* __restrict__ hist, const int* __restrict__ psum,
                         const int* __restrict__ bstart) {
    int bin = blockIdx.x * 256 + threadIdx.x;
    int ch = blockIdx.y;
    if (bin >= NB) return;
    int run = bstart[bin] + psum[ch * NB + bin];
    for (int seg = ch * SEGPC; seg < (ch + 1) * SEGPC; ++seg) {
        int idx = seg * NB + bin;
        int v = hist[idx];
        hist[idx] = run;
        run += v;
    }
}

// ---- phase 3: LDS-sorted scatter, coalesced int2 writes --------------------
// record: .x = row | (col&63)<<17 ; .y = w_half | bin<<16 (bin bits scrubbed later)

__launch_bounds__(256)
__global__ void k_scatter(const int* __restrict__ row, const int* __restrict__ col,
                          const float* __restrict__ w, const int* __restrict__ hist,
                          int2* __restrict__ bkt) {
    __shared__ int bins[NB];
    __shared__ int cur[NB];
    __shared__ int lsum[256];
    __shared__ int2 sdata[EPS];
    int seg = blockIdx.x, tid = threadIdx.x;
    for (int i = tid; i < NB; i += 256) bins[i] = 0;
    __syncthreads();
    int base = seg * EPS;
    for (int k = tid; k < EPS; k += 256) atomicAdd(&bins[col[base + k] >> 6], 1);
    __syncthreads();
    // block exclusive scan of bins
    const int M = (NB + 255) / 256;
    int lbase = tid * M;
    int s = 0;
    for (int q = 0; q < M; ++q) { int i = lbase + q; if (i < NB) s += bins[i]; }
    lsum[tid] = s; __syncthreads();
    for (int off = 1; off < 256; off <<= 1) {
        int add = (tid >= off) ? lsum[tid - off] : 0;
        __syncthreads(); lsum[tid] += add; __syncthreads();
    }
    int run = (tid > 0) ? lsum[tid - 1] : 0;
    for (int q = 0; q < M; ++q) {
        int i = lbase + q;
        if (i < NB) { int v = bins[i]; bins[i] = run; cur[i] = run; run += v; }
    }
    __syncthreads();
    // place into LDS sorted by bin
    for (int k = tid; k < EPS; k += 256) {
        int e = base + k;
        int r = row[e], c = col[e];
        int bin = c >> 6;
        int pos = atomicAdd(&cur[bin], 1);
        sdata[pos] = make_int2(r | ((c & 63) << 17), f2h_us(w[e]) | (bin << 16));
    }
    __syncthreads();
    // bins[bin] := global_start(seg,bin) - lds_start(bin)
    for (int i = tid; i < NB; i += 256) bins[i] = hist[seg * NB + i] - bins[i];
    __syncthreads();
    for (int j = tid; j < EPS; j += 256) {
        int2 d = sdata[j];
        int bin = ((unsigned)d.y) >> 16;
        bkt[bins[bin] + j] = d;
    }
}

// ---- phase 4: per-bucket refine to node order ------------------------------
// single global read (records cached in registers), coalesced write-back

__launch_bounds__(256)
__global__ void k_refine(const int* __restrict__ bstart, int2* __restrict__ bkt,
                         float* __restrict__ dinv, int* __restrict__ ns) {
    __shared__ int cnt[NPB];
    __shared__ int cur[NPB];
    __shared__ float wdeg[NPB];
    __shared__ int2 sorted[CAP];
    int2 cache[(CAP + 255) / 256];   // <= 12 records per thread
    int b = blockIdx.x, tid = threadIdx.x;
    int s = bstart[b], e = bstart[b + 1];
    int size = e - s; if (size > CAP) size = CAP;   // 22-sigma guard, never hit
    if (tid < NPB) { cnt[tid] = 0; wdeg[tid] = 1.0f; }   // self-loop weight
    __syncthreads();
    int nloc = 0;
    for (int k = tid; k < size; k += 256) {
        int2 d = bkt[s + k];
        cache[nloc++] = d;
        int cl = (d.x >> 17) & 63;
        atomicAdd(&cnt[cl], 1);
        atomicAdd(&wdeg[cl], h2f_lo(d.y));
    }
    __syncthreads();
    int v = (tid < NPB) ? cnt[tid] : 0;
    for (int off = 1; off < NPB; off <<= 1) {
        int add = (tid >= off && tid < NPB) ? cnt[tid - off] : 0;
        __syncthreads();
        if (tid < NPB) cnt[tid] += add;
        __syncthreads();
    }
    if (tid < NPB) {
        int excl = cnt[tid] - v;
        cur[tid] = excl;
        int node = b * NPB + tid;
        if (node < NN) { ns[node] = s + excl; dinv[node] = rsqrtf(wdeg[tid]); }
    }
    if (b == NB - 1 && tid == 0) ns[NN] = e;
    __syncthreads();
    for (int q = 0; q < nloc; ++q) {
        int2 d = cache[q];
        int cl = (d.x >> 17) & 63;
        int pos = atomicAdd(&cur[cl], 1);
        sorted[pos] = make_int2(d.x & 0x1FFFF, d.y & 0xFFFF);
    }
    __syncthreads();
    for (int k = tid; k < size; k += 256) bkt[s + k] = sorted[k];
}

// ---- x @ W1, pre-scaled by dinv, fp16 out ----------------------------------
// 16 lanes per node; W1 transposed in LDS so each thread reads ds_read_b128.

__launch_bounds__(256)
__global__ void k_xw(const float* __restrict__ x, const float* __restrict__ W1,
                     const float* __restrict__ dinv, unsigned short* __restrict__ xws) {
    __shared__ float w1t[HID * W1STRIDE];
    for (int idx = threadIdx.x; idx < FIN * HID; idx += 256) {
        int k = idx >> 4, c = idx & 15;
        w1t[c * W1STRIDE + k] = W1[idx];
    }
    __syncthreads();
    int t = blockIdx.x * 256 + threadIdx.x;
    int node = t >> 4, c = t & 15;
    const float4* xr = (const float4*)(x + (long)node * FIN);   // 300 = 75*4
    const float4* wr = (const float4*)(w1t + c * W1STRIDE);
    float acc = 0.f;
    #pragma unroll 5
    for (int q = 0; q < FIN / 4; ++q) {
        float4 xf = xr[q];
        float4 wf = wr[q];
        acc = fmaf(xf.x, wf.x, acc);
        acc = fmaf(xf.y, wf.y, acc);
        acc = fmaf(xf.z, wf.z, acc);
        acc = fmaf(xf.w, wf.w, acc);
    }
    xws[node * HID + c] = (unsigned short)f2h_us(dinv[node] * acc);
}

// ---- layer 1 pull-gather, fused b1/relu/@W2 --------------------------------

__global__ void k_gather1(const int* __restrict__ ns, const int2* __restrict__ bkt,
                          const unsigned short* __restrict__ xwsh,
                          const float* __restrict__ dinv, const float* __restrict__ b1,
                          const float* __restrict__ W2, unsigned short* __restrict__ hw2s) {
    __shared__ float w2s[HID * NC];
    __shared__ float b1s[HID];
    if (threadIdx.x < HID * NC) w2s[threadIdx.x] = W2[threadIdx.x];
    if (threadIdx.x < HID) b1s[threadIdx.x] = b1[threadIdx.x];
    __syncthreads();
    int t = blockIdx.x * 256 + threadIdx.x;
    int i = t >> 4, c = t & 15;
    int s = ns[i], e = ns[i + 1];
    float acc = 0.f;
    int k = s;
    for (; k + 4 <= e; k += 4) {
        int2 e0 = bkt[k], e1 = bkt[k + 1], e2 = bkt[k + 2], e3 = bkt[k + 3];
        __half_raw h0; h0.x = xwsh[e0.x * HID + c];
        __half_raw h1; h1.x = xwsh[e1.x * HID + c];
        __half_raw h2; h2.x = xwsh[e2.x * HID + c];
        __half_raw h3; h3.x = xwsh[e3.x * HID + c];
        acc = fmaf(h2f_lo(e0.y), __half2float(*(__half*)&h0), acc);
        acc = fmaf(h2f_lo(e1.y), __half2float(*(__half*)&h1), acc);
        acc = fmaf(h2f_lo(e2.y), __half2float(*(__half*)&h2), acc);
        acc = fmaf(h2f_lo(e3.y), __half2float(*(__half*)&h3), acc);
    }
    for (; k < e; ++k) {
        int2 e0 = bkt[k];
        __half_raw h0; h0.x = xwsh[e0.x * HID + c];
        acc = fmaf(h2f_lo(e0.y), __half2float(*(__half*)&h0), acc);
    }
    { __half_raw hs; hs.x = xwsh[i * HID + c]; acc += __half2float(*(__half*)&hs); }
    float dc = dinv[i];
    float h = fmaxf(fmaf(dc, acc, b1s[c]), 0.f);
    float acc2 = 0.f;
    int jj = (c < NC) ? c : 0;
    #pragma unroll
    for (int k2 = 0; k2 < HID; ++k2) {
        float hk = __shfl(h, k2, HID);
        acc2 = fmaf(hk, w2s[k2 * NC + jj], acc2);
    }
    if (c < NC) hw2s[i * NC + c] = (unsigned short)f2h_us(dc * acc2);
}

// ---- layer 2 pull-gather, fused b2/log_softmax -----------------------------

__global__ void k_gather2(const int* __restrict__ ns, const int2* __restrict__ bkt,
                          const unsigned short* __restrict__ hw2s,
                          const float* __restrict__ dinv, const float* __restrict__ b2,
                          float* __restrict__ out) {
    int t = blockIdx.x * 256 + threadIdx.x;
    int i = t >> 4, j = t & 15;
    int s = ns[i], e = ns[i + 1];
    float v;
    if (j < NC) {
        float acc = 0.f;
        int k = s;
        for (; k + 4 <= e; k += 4) {
            int2 e0 = bkt[k], e1 = bkt[k + 1], e2 = bkt[k + 2], e3 = bkt[k + 3];
            __half_raw h0; h0.x = hw2s[e0.x * NC + j];
            __half_raw h1; h1.x = hw2s[e1.x * NC + j];
            __half_raw h2; h2.x = hw2s[e2.x * NC + j];
            __half_raw h3; h3.x = hw2s[e3.x * NC + j];
            acc = fmaf(h2f_lo(e0.y), __half2float(*(__half*)&h0), acc);
            acc = fmaf(h2f_lo(e1.y), __half2float(*(__half*)&h1), acc);
            acc = fmaf(h2f_lo(e2.y), __half2float(*(__half*)&h2), acc);
            acc = fmaf(h2f_lo(e3.y), __half2float(*(__half*)&h3), acc);
        }
        for (; k < e; ++k) {
            int2 e0 = bkt[k];
            __half_raw h0; h0.x = hw2s[e0.x * NC + j];
            acc = fmaf(h2f_lo(e0.y), __half2float(*(__half*)&h0), acc);
        }
        { __half_raw hs; hs.x = hw2s[i * NC + j]; acc += __half2float(*(__half*)&hs); }
        v = fmaf(dinv[i], acc, b2[j]);
    } else {
        v = -1e30f;
    }
    float m = v;
    #pragma unroll
    for (int mask = 8; mask > 0; mask >>= 1) m = fmaxf(m, __shfl_xor(m, mask, HID));
    float ev = (j < NC) ? __expf(v - m) : 0.f;
    float ssum = ev;
    #pragma unroll
    for (int mask = 8; mask > 0; mask >>= 1) ssum += __shfl_xor(ssum, mask, HID);
    if (j < NC) out[(long)i * NC + j] = v - m - __logf(ssum);
}

// ---- launch -----------------------------------------------------------------

extern "C" void kernel_launch(void* const* d_in, const int* in_sizes, int n_in,
                              void* d_out, int out_size, void* d_ws, size_t ws_size,
                              hipStream_t stream) {
    const float* x  = (const float*)d_in[0];
    const int*   ei = (const int*)d_in[1];
    const float* ew = (const float*)d_in[2];
    const float* W1 = (const float*)d_in[3];
    const float* b1 = (const float*)d_in[4];
    const float* W2 = (const float*)d_in[5];
    const float* b2 = (const float*)d_in[6];
    float* out = (float*)d_out;

    const int* row = ei;
    const int* col = ei + NE;

    // workspace (words); xws overlays hist (dead after k_scatter)
    int*   hist   = (int*)d_ws;                    // NSEG*NB = 800,256
    int*   psum   = hist + NSEG * NB;              // NCH*NB  = 12,504
    int*   bstart = psum + NCH * NB;               // NB+1    = 1,564
    float* dinv   = (float*)(bstart + NB + 1);     // 100,000
    int*   ns     = (int*)(dinv + NN);             // 100,001
    size_t o = (size_t)(NSEG * NB) + NCH * NB + (NB + 1) + NN + (NN + 1);
    o = (o + 1) & ~(size_t)1;                      // 8B align for int2
    int2*  bkt    = (int2*)((int*)d_ws + o);       // NE int2 = 6,400,000 w
    unsigned short* hw2s = (unsigned short*)(bkt + NE);   // NN*NC halves = 500,000 h
    unsigned short* xws  = (unsigned short*)hist;  // NN*HID halves overlay
    // total ~= 7,914,326 words = 31.7 MB (proven)

    k_hist<<<NSEG, 256, 0, stream>>>(col, hist);
    k_psumA<<<dim3((NB + 255) / 256, NCH), 256, 0, stream>>>(hist, psum);
    k_psumB<<<(NB + 255) / 256, 256, 0, stream>>>(psum, bstart);
    k_scanBkt<<<1, 256, 0, stream>>>(bstart);
    k_applyC<<<dim3((NB + 255) / 256, NCH), 256, 0, stream>>>(hist, psum, bstart);
    k_scatter<<<NSEG, 256, 0, stream>>>(row, col, ew, hist, bkt);
    k_refine<<<NB, 256, 0, stream>>>(bstart, bkt, dinv, ns);

    k_xw<<<(NN * 16) / 256, 256, 0, stream>>>(x, W1, dinv, xws);
    k_gather1<<<(NN * 16) / 256, 256, 0, stream>>>(ns, bkt, xws, dinv, b1, W2, hw2s);
    k_gather2<<<(NN * 16) / 256, 256, 0, stream>>>(ns, bkt, hw2s, dinv, b2, out);
}